// Round 1
// baseline (77.674 us; speedup 1.0000x reference)
//
#include <hip/hip_runtime.h>
#include <math.h>

#define NS 96
#define NSEG 95

// ---------------------------------------------------------------------------
// Kernel 0: init workspace min/max accumulators (uint-encoded positive floats)
// ---------------------------------------------------------------------------
__global__ void init_mm_kernel(unsigned* mm) {
    mm[0] = 0x7F7FFFFFu;  // FLT_MAX bits  -> min accumulator
    mm[1] = 0u;           // 0.0f bits     -> max accumulator (depths > 0)
}

// ---------------------------------------------------------------------------
// Kernel 1: global min/max of depths. depths sorted ascending along S, so
// min = min over rays of depths[ray][0], max = max over rays of depths[ray][95].
// ---------------------------------------------------------------------------
__global__ __launch_bounds__(256) void minmax_kernel(
    const float* __restrict__ depths, unsigned* mm, int n_rays)
{
    int idx = blockIdx.x * blockDim.x + threadIdx.x;
    float lo = __int_as_float(0x7F7FFFFF);
    float hi = 0.0f;
    if (idx < n_rays) {
        lo = depths[(size_t)idx * NS];
        hi = depths[(size_t)idx * NS + (NS - 1)];
    }
#pragma unroll
    for (int off = 32; off; off >>= 1) {
        lo = fminf(lo, __shfl_xor(lo, off));
        hi = fmaxf(hi, __shfl_xor(hi, off));
    }
    if ((threadIdx.x & 63) == 0) {
        atomicMin(&mm[0], __float_as_uint(lo));
        atomicMax(&mm[1], __float_as_uint(hi));
    }
}

// ---------------------------------------------------------------------------
// Per-segment alpha / (1 - alpha + 1e-10)
// softplus matches jax.nn.softplus = logaddexp(x, 0) = max(x,0)+log1p(exp(-|x|))
// ---------------------------------------------------------------------------
__device__ __forceinline__ float seg_am(float d0, float d1, float n0, float n1,
                                        float& alpha) {
    float delta = d1 - d0;
    float x  = (n0 + n1) * 0.5f - 1.0f;
    float sp = fmaxf(x, 0.0f) + log1pf(expf(-fabsf(x)));
    alpha = 1.0f - expf(-sp * delta);
    return (1.0f - alpha) + 1e-10f;
}

// ---------------------------------------------------------------------------
// Kernel 2: one wave (64 lanes) per ray. Lane l owns segments l and 64+l.
// Exclusive cumprod across 95 segments via two wave scans + chunk carry.
// ---------------------------------------------------------------------------
__global__ __launch_bounds__(256) void raymarch_kernel(
    const float* __restrict__ colors,
    const float* __restrict__ densities,
    const float* __restrict__ depths,
    const unsigned* __restrict__ mm,
    float* __restrict__ out_rgb,
    float* __restrict__ out_depth,
    float* __restrict__ out_w,
    int n_rays)
{
    const int lane = threadIdx.x & 63;
    const int ray  = blockIdx.x * (blockDim.x >> 6) + (threadIdx.x >> 6);
    if (ray >= n_rays) return;

    const float* dep = depths    + (size_t)ray * NS;
    const float* den = densities + (size_t)ray * NS;
    const float* col = colors    + (size_t)ray * NS * 3;

    // ---- chunk 0: segment j = lane (0..63, all < 95) ----
    float d0 = dep[lane], d1 = dep[lane + 1];
    float a0;
    float am0 = seg_am(d0, d1, den[lane], den[lane + 1], a0);
    float cm00 = (col[lane * 3 + 0] + col[lane * 3 + 3]) * 0.5f;
    float cm01 = (col[lane * 3 + 1] + col[lane * 3 + 4]) * 0.5f;
    float cm02 = (col[lane * 3 + 2] + col[lane * 3 + 5]) * 0.5f;
    float dm0  = (d0 + d1) * 0.5f;

    // ---- chunk 1: segment j = 64 + lane (valid for lane < 31) ----
    const bool v1 = lane < (NSEG - 64);
    float a1 = 0.0f, am1 = 1.0f, cm10 = 0.0f, cm11 = 0.0f, cm12 = 0.0f, dm1 = 0.0f;
    if (v1) {
        int j = 64 + lane;
        float e0 = dep[j], e1 = dep[j + 1];
        am1 = seg_am(e0, e1, den[j], den[j + 1], a1);
        cm10 = (col[j * 3 + 0] + col[j * 3 + 3]) * 0.5f;
        cm11 = (col[j * 3 + 1] + col[j * 3 + 4]) * 0.5f;
        cm12 = (col[j * 3 + 2] + col[j * 3 + 5]) * 0.5f;
        dm1  = (e0 + e1) * 0.5f;
    }

    // ---- inclusive product scan of chunk 0 (Hillis-Steele over 64 lanes) ----
    float p0 = am0;
#pragma unroll
    for (int off = 1; off < 64; off <<= 1) {
        float t = __shfl_up(p0, off);
        if (lane >= off) p0 *= t;
    }
    float t0 = __shfl_up(p0, 1);
    float T0 = lane ? t0 : 1.0f;          // exclusive transmittance for j = lane
    float total0 = __shfl(p0, 63);        // product of all chunk-0 factors

    // ---- inclusive product scan of chunk 1 (invalid lanes carry 1.0) ----
    float p1 = am1;
#pragma unroll
    for (int off = 1; off < 64; off <<= 1) {
        float t = __shfl_up(p1, off);
        if (lane >= off) p1 *= t;
    }
    float t1 = __shfl_up(p1, 1);
    float T1 = total0 * (lane ? t1 : 1.0f);

    float w0 = a0 * T0;
    float w1 = v1 ? a1 * T1 : 0.0f;

    // ---- weights output ----
    out_w[(size_t)ray * NSEG + lane] = w0;
    if (v1) out_w[(size_t)ray * NSEG + 64 + lane] = w1;

    // ---- composite reductions (5 values) ----
    float sr = w0 * cm00 + w1 * cm10;
    float sg = w0 * cm01 + w1 * cm11;
    float sb = w0 * cm02 + w1 * cm12;
    float sw = w0 + w1;
    float sd = w0 * dm0 + w1 * dm1;
#pragma unroll
    for (int off = 32; off; off >>= 1) {
        sr += __shfl_xor(sr, off);
        sg += __shfl_xor(sg, off);
        sb += __shfl_xor(sb, off);
        sw += __shfl_xor(sw, off);
        sd += __shfl_xor(sd, off);
    }

    if (lane == 0) {
        float cd = sd / sw;
        if (isnan(cd)) cd = __int_as_float(0x7F800000);  // nan -> +inf
        float gmin = __uint_as_float(mm[0]);
        float gmax = __uint_as_float(mm[1]);
        cd = fminf(fmaxf(cd, gmin), gmax);               // clip to global range
        out_depth[ray] = cd;
        out_rgb[(size_t)ray * 3 + 0] = sr * 2.0f - 1.0f;
        out_rgb[(size_t)ray * 3 + 1] = sg * 2.0f - 1.0f;
        out_rgb[(size_t)ray * 3 + 2] = sb * 2.0f - 1.0f;
    }
}

// ---------------------------------------------------------------------------
extern "C" void kernel_launch(void* const* d_in, const int* in_sizes, int n_in,
                              void* d_out, int out_size, void* d_ws, size_t ws_size,
                              hipStream_t stream) {
    const float* colors    = (const float*)d_in[0];
    const float* densities = (const float*)d_in[1];
    const float* depths    = (const float*)d_in[2];

    const int n_rays = in_sizes[1] / NS;  // densities is B*R*S

    float* out       = (float*)d_out;
    float* out_rgb   = out;                              // [n_rays, 3]
    float* out_depth = out + (size_t)n_rays * 3;         // [n_rays, 1]
    float* out_w     = out + (size_t)n_rays * 4;         // [n_rays, 95]

    unsigned* mm = (unsigned*)d_ws;

    hipLaunchKernelGGL(init_mm_kernel, dim3(1), dim3(1), 0, stream, mm);
    hipLaunchKernelGGL(minmax_kernel, dim3((n_rays + 255) / 256), dim3(256), 0,
                       stream, depths, mm, n_rays);

    const int rays_per_block = 4;  // 256 threads = 4 waves
    hipLaunchKernelGGL(raymarch_kernel,
                       dim3((n_rays + rays_per_block - 1) / rays_per_block),
                       dim3(256), 0, stream,
                       colors, densities, depths, mm,
                       out_rgb, out_depth, out_w, n_rays);
}

// Round 2
// 57.196 us; speedup vs baseline: 1.3580x; 1.3580x over previous
//
#include <hip/hip_runtime.h>
#include <math.h>

#define NS 96
#define NSEG 95
#define LPR 8    // lanes per ray
#define SPL 12   // segments per lane (8*12 = 96 slots, slot 95 is fake)

// ---------------------------------------------------------------------------
// Kernel 0: init workspace min/max accumulators (uint-encoded positive floats)
// ---------------------------------------------------------------------------
__global__ void init_mm_kernel(unsigned* mm) {
    mm[0] = 0x7F7FFFFFu;  // FLT_MAX bits  -> min accumulator
    mm[1] = 0u;           // 0.0f bits     -> max accumulator (depths > 0)
}

// ---------------------------------------------------------------------------
// Kernel 1: global min/max of depths — coalesced float4 grid-stride sweep,
// wave shuffle reduce + per-block LDS reduce -> 2 atomics per block.
// (uint-ordered atomics valid because depths > 0)
// ---------------------------------------------------------------------------
__global__ __launch_bounds__(256) void minmax_kernel(
    const float4* __restrict__ dep4, unsigned* mm, int n4)
{
    int idx = blockIdx.x * blockDim.x + threadIdx.x;
    int stride = gridDim.x * blockDim.x;
    float lo = __int_as_float(0x7F7FFFFF);
    float hi = 0.0f;
    for (int i = idx; i < n4; i += stride) {
        float4 v = dep4[i];
        lo = fminf(lo, fminf(fminf(v.x, v.y), fminf(v.z, v.w)));
        hi = fmaxf(hi, fmaxf(fmaxf(v.x, v.y), fmaxf(v.z, v.w)));
    }
#pragma unroll
    for (int off = 32; off; off >>= 1) {
        lo = fminf(lo, __shfl_xor(lo, off));
        hi = fmaxf(hi, __shfl_xor(hi, off));
    }
    __shared__ float slo[4], shi[4];
    int wave = threadIdx.x >> 6;
    if ((threadIdx.x & 63) == 0) { slo[wave] = lo; shi[wave] = hi; }
    __syncthreads();
    if (threadIdx.x == 0) {
        lo = fminf(fminf(slo[0], slo[1]), fminf(slo[2], slo[3]));
        hi = fmaxf(fmaxf(shi[0], shi[1]), fmaxf(shi[2], shi[3]));
        atomicMin(&mm[0], __float_as_uint(lo));
        atomicMax(&mm[1], __float_as_uint(hi));
    }
}

// ---------------------------------------------------------------------------
// Kernel 2: 8 lanes per ray, 12 contiguous segments per lane.
// Serial in-register cumprod per lane; 3-step shfl_up scan across the 8-lane
// group; 3-step shfl_xor butterflies for the 5 composites.
// ---------------------------------------------------------------------------
__global__ __launch_bounds__(256) void raymarch_kernel(
    const float* __restrict__ colors,
    const float* __restrict__ densities,
    const float* __restrict__ depths,
    const unsigned* __restrict__ mm,
    float* __restrict__ out_rgb,
    float* __restrict__ out_depth,
    float* __restrict__ out_w,
    int n_rays)
{
    const int lane = threadIdx.x & 63;
    const int sub  = lane & (LPR - 1);      // lane within ray group (0..7)
    const int grp  = lane >> 3;             // ray within wave (0..7)
    const int wave = threadIdx.x >> 6;      // wave within block (0..3)
    const int ray  = blockIdx.x * 32 + wave * 8 + grp;
    if (ray >= n_rays) return;

    const int s0 = sub * SPL;               // first sample of this lane's chunk
    const bool last = (sub == LPR - 1);     // lane owning the fake segment 95

    const float* dep = depths    + (size_t)ray * NS + s0;         // 16B aligned
    const float* den = densities + (size_t)ray * NS + s0;         // 16B aligned
    const float* col = colors    + (size_t)ray * NS * 3 + s0 * 3; // 16B aligned

    // ---- load 13 depths / densities (13th predicated off for last lane) ----
    float d[13], nd[13];
#pragma unroll
    for (int q = 0; q < 3; ++q) {
        float4 v = *(const float4*)(dep + 4 * q);
        d[4 * q + 0] = v.x; d[4 * q + 1] = v.y; d[4 * q + 2] = v.z; d[4 * q + 3] = v.w;
        float4 u = *(const float4*)(den + 4 * q);
        nd[4 * q + 0] = u.x; nd[4 * q + 1] = u.y; nd[4 * q + 2] = u.z; nd[4 * q + 3] = u.w;
    }
    d[12]  = last ? 0.0f : dep[12];
    nd[12] = last ? 0.0f : den[12];

    // ---- per-segment e_j = exp(-softplus(mid_density-1) * delta) ----------
    float e[SPL];
#pragma unroll
    for (int j = 0; j < SPL; ++j) {
        float delta = d[j + 1] - d[j];
        float x  = (nd[j] + nd[j + 1]) * 0.5f - 1.0f;
        float sp = fmaxf(x, 0.0f) + log1pf(expf(-fabsf(x)));
        e[j] = expf(-sp * delta);
    }
    if (last) e[SPL - 1] = 1.0f;   // fake segment 95: alpha=0, am=1+1e-10

    // ---- local product, 3-step inclusive scan over the 8-lane group -------
    float P = 1.0f;
#pragma unroll
    for (int j = 0; j < SPL; ++j) P *= (e[j] + 1e-10f);
    float inc = P;
#pragma unroll
    for (int off = 1; off < LPR; off <<= 1) {
        float t = __shfl_up(inc, off, LPR);
        if (sub >= off) inc *= t;
    }
    float Tex = __shfl_up(inc, 1, LPR);
    if (sub == 0) Tex = 1.0f;      // exclusive transmittance at chunk start

    // ---- colors: 36 floats (+4 more for non-last lanes) --------------------
    float c[40];
#pragma unroll
    for (int q = 0; q < 9; ++q) {
        float4 v = *(const float4*)(col + 4 * q);
        c[4 * q + 0] = v.x; c[4 * q + 1] = v.y; c[4 * q + 2] = v.z; c[4 * q + 3] = v.w;
    }
    if (!last) {
        float4 v = *(const float4*)(col + 36);
        c[36] = v.x; c[37] = v.y; c[38] = v.z; c[39] = v.w;
    } else {
        c[36] = c[37] = c[38] = c[39] = 0.0f;
    }

    // ---- main serial loop: weights + composites ----------------------------
    float* wp = out_w + (size_t)ray * NSEG + s0;
    float Trun = Tex;
    float sr = 0.f, sg = 0.f, sb = 0.f, sw = 0.f, sd = 0.f;
#pragma unroll
    for (int j = 0; j < SPL; ++j) {
        float alpha = 1.0f - e[j];
        float w = alpha * Trun;
        Trun *= (e[j] + 1e-10f);
        if (!last || j < SPL - 1) wp[j] = w;
        float dm = (d[j] + d[j + 1]) * 0.5f;
        float cr = (c[3 * j + 0] + c[3 * j + 3]) * 0.5f;
        float cg = (c[3 * j + 1] + c[3 * j + 4]) * 0.5f;
        float cb = (c[3 * j + 2] + c[3 * j + 5]) * 0.5f;
        sr += w * cr; sg += w * cg; sb += w * cb;
        sw += w; sd += w * dm;
    }

    // ---- reduce the 5 composites across the 8-lane group -------------------
#pragma unroll
    for (int off = 4; off; off >>= 1) {
        sr += __shfl_xor(sr, off);
        sg += __shfl_xor(sg, off);
        sb += __shfl_xor(sb, off);
        sw += __shfl_xor(sw, off);
        sd += __shfl_xor(sd, off);
    }

    if (sub == 0) {
        float cd = sd / sw;
        if (isnan(cd)) cd = __int_as_float(0x7F800000);  // nan -> +inf
        float gmin = __uint_as_float(mm[0]);
        float gmax = __uint_as_float(mm[1]);
        cd = fminf(fmaxf(cd, gmin), gmax);
        out_depth[ray] = cd;
        out_rgb[(size_t)ray * 3 + 0] = sr * 2.0f - 1.0f;
        out_rgb[(size_t)ray * 3 + 1] = sg * 2.0f - 1.0f;
        out_rgb[(size_t)ray * 3 + 2] = sb * 2.0f - 1.0f;
    }
}

// ---------------------------------------------------------------------------
extern "C" void kernel_launch(void* const* d_in, const int* in_sizes, int n_in,
                              void* d_out, int out_size, void* d_ws, size_t ws_size,
                              hipStream_t stream) {
    const float* colors    = (const float*)d_in[0];
    const float* densities = (const float*)d_in[1];
    const float* depths    = (const float*)d_in[2];

    const int n_rays = in_sizes[1] / NS;  // densities is B*R*S

    float* out       = (float*)d_out;
    float* out_rgb   = out;                              // [n_rays, 3]
    float* out_depth = out + (size_t)n_rays * 3;         // [n_rays, 1]
    float* out_w     = out + (size_t)n_rays * 4;         // [n_rays, 95]

    unsigned* mm = (unsigned*)d_ws;

    hipLaunchKernelGGL(init_mm_kernel, dim3(1), dim3(1), 0, stream, mm);

    const int n4 = n_rays * NS / 4;
    hipLaunchKernelGGL(minmax_kernel, dim3(512), dim3(256), 0, stream,
                       (const float4*)depths, mm, n4);

    const int rays_per_block = 32;  // 256 threads = 4 waves * 8 rays/wave
    hipLaunchKernelGGL(raymarch_kernel,
                       dim3((n_rays + rays_per_block - 1) / rays_per_block),
                       dim3(256), 0, stream,
                       colors, densities, depths, mm,
                       out_rgb, out_depth, out_w, n_rays);
}

// Round 3
// 56.265 us; speedup vs baseline: 1.3805x; 1.0166x over previous
//
#include <hip/hip_runtime.h>
#include <math.h>

#define NS 96
#define NSEG 95
#define LPR 8    // lanes per ray
#define SPL 12   // segments per lane (8*12 = 96 slots, slot 95 is fake)
#define RPB 32   // rays per block (256 threads = 4 waves * 8 rays/wave)

__device__ __forceinline__ float fast_exp2(float x) {
#if __has_builtin(__builtin_amdgcn_exp2f)
    return __builtin_amdgcn_exp2f(x);
#else
    return exp2f(x);
#endif
}
__device__ __forceinline__ float fast_log2(float x) {
#if __has_builtin(__builtin_amdgcn_logf)
    return __builtin_amdgcn_logf(x);
#else
    return log2f(x);
#endif
}

// ---------------------------------------------------------------------------
// Kernel 0: init workspace min/max accumulators (uint-encoded positive floats)
// ---------------------------------------------------------------------------
__global__ void init_mm_kernel(unsigned* mm) {
    mm[0] = 0x7F7FFFFFu;  // FLT_MAX bits  -> min accumulator
    mm[1] = 0u;           // 0.0f bits     -> max accumulator (depths > 0)
}

// ---------------------------------------------------------------------------
// Kernel 1: global min/max of depths — coalesced float4 grid-stride sweep.
// ---------------------------------------------------------------------------
__global__ __launch_bounds__(256) void minmax_kernel(
    const float4* __restrict__ dep4, unsigned* mm, int n4)
{
    int idx = blockIdx.x * blockDim.x + threadIdx.x;
    int stride = gridDim.x * blockDim.x;
    float lo = __int_as_float(0x7F7FFFFF);
    float hi = 0.0f;
    for (int i = idx; i < n4; i += stride) {
        float4 v = dep4[i];
        lo = fminf(lo, fminf(fminf(v.x, v.y), fminf(v.z, v.w)));
        hi = fmaxf(hi, fmaxf(fmaxf(v.x, v.y), fmaxf(v.z, v.w)));
    }
#pragma unroll
    for (int off = 32; off; off >>= 1) {
        lo = fminf(lo, __shfl_xor(lo, off));
        hi = fmaxf(hi, __shfl_xor(hi, off));
    }
    __shared__ float slo[4], shi[4];
    int wave = threadIdx.x >> 6;
    if ((threadIdx.x & 63) == 0) { slo[wave] = lo; shi[wave] = hi; }
    __syncthreads();
    if (threadIdx.x == 0) {
        lo = fminf(fminf(slo[0], slo[1]), fminf(slo[2], slo[3]));
        hi = fmaxf(fmaxf(shi[0], shi[1]), fmaxf(shi[2], shi[3]));
        atomicMin(&mm[0], __float_as_uint(lo));
        atomicMax(&mm[1], __float_as_uint(hi));
    }
}

// ---------------------------------------------------------------------------
// Kernel 2: LDS-staged. Block stages 32 rays (colors/densities/depths) with
// fully coalesced float4 loads, then 8 lanes/ray consume 12 contiguous
// segments each from LDS (padded strides 292 / 100 floats -> conflict-free).
// ---------------------------------------------------------------------------
__global__ __launch_bounds__(256) void raymarch_kernel(
    const float4* __restrict__ col4,
    const float4* __restrict__ den4,
    const float4* __restrict__ dep4,
    const unsigned* __restrict__ mm,
    float* __restrict__ out_rgb,
    float* __restrict__ out_depth,
    float* __restrict__ out_w,
    int n_rays)
{
    __shared__ float4 sc[RPB * 73];    // colors: 73 f4 (292 floats) per ray
    __shared__ float4 sdep[RPB * 25];  // depths: 25 f4 (100 floats) per ray
    __shared__ float4 sden[RPB * 25];  // densities

    const int tid  = threadIdx.x;
    const int base = blockIdx.x * RPB;

    // ---- coalesced staging -------------------------------------------------
    {
        const float4* g = col4 + (size_t)base * 72;
        const int nf4c = (n_rays - base) * 72;   // f4s remaining from base
#pragma unroll
        for (int q = 0; q < 9; ++q) {
            int f = tid + 256 * q;               // 0..2303
            if (f < nf4c) {
                int r = f / 72, w = f - r * 72;
                sc[r * 73 + w] = g[f];
            }
        }
        const float4* gd = dep4 + (size_t)base * 24;
        const float4* gn = den4 + (size_t)base * 24;
        const int nf4d = (n_rays - base) * 24;
#pragma unroll
        for (int q = 0; q < 3; ++q) {
            int f = tid + 256 * q;               // 0..767
            if (f < nf4d) {
                int r = f / 24, w = f - r * 24;
                sdep[r * 25 + w] = gd[f];
                sden[r * 25 + w] = gn[f];
            }
        }
    }
    __syncthreads();

    const int lane = tid & 63;
    const int sub  = lane & (LPR - 1);
    const int grp  = lane >> 3;
    const int wv   = tid >> 6;
    const int rloc = wv * 8 + grp;
    const int ray  = base + rloc;
    if (ray >= n_rays) return;

    const float* ldep = (const float*)&sdep[rloc * 25];
    const float* lden = (const float*)&sden[rloc * 25];
    const float* lcol = (const float*)&sc[rloc * 73];
    const int s0 = sub * SPL;
    const bool last = (sub == LPR - 1);

    // ---- 13 depths / densities from LDS ------------------------------------
    float d[13], nd[13];
#pragma unroll
    for (int q = 0; q < 3; ++q) {
        float4 v = *(const float4*)(ldep + s0 + 4 * q);
        d[4 * q + 0] = v.x; d[4 * q + 1] = v.y; d[4 * q + 2] = v.z; d[4 * q + 3] = v.w;
        float4 u = *(const float4*)(lden + s0 + 4 * q);
        nd[4 * q + 0] = u.x; nd[4 * q + 1] = u.y; nd[4 * q + 2] = u.z; nd[4 * q + 3] = u.w;
    }
    d[12]  = ldep[s0 + 12];
    nd[12] = lden[s0 + 12];
    if (last) { d[12] = 0.0f; nd[12] = 0.0f; }   // garbage guard (pad region)

    // ---- 40 colors from LDS -------------------------------------------------
    float c[40];
#pragma unroll
    for (int q = 0; q < 10; ++q) {
        float4 v = *(const float4*)(lcol + sub * 36 + 4 * q);
        c[4 * q + 0] = v.x; c[4 * q + 1] = v.y; c[4 * q + 2] = v.z; c[4 * q + 3] = v.w;
    }
    if (last) { c[36] = c[37] = c[38] = c[39] = 0.0f; }

    // ---- e_j = exp(-softplus(mid-1)*delta) via native exp2/log2 ------------
    // softplus(x)*log2e = log2(1 + 2^(x*log2e));  e = 2^(-delta * that)
    const float LOG2E = 1.4426950408889634f;
    float e[SPL];
#pragma unroll
    for (int j = 0; j < SPL; ++j) {
        float delta = d[j + 1] - d[j];
        float x  = (nd[j] + nd[j + 1]) * 0.5f - 1.0f;
        float u  = fast_exp2(x * LOG2E);
        float sp2 = fast_log2(1.0f + u);
        e[j] = fast_exp2(-delta * sp2);
    }
    if (last) e[SPL - 1] = 1.0f;   // fake segment 95: alpha=0, am=1+1e-10

    // ---- local product, 3-step inclusive scan over the 8-lane group -------
    float P = 1.0f;
#pragma unroll
    for (int j = 0; j < SPL; ++j) P *= (e[j] + 1e-10f);
    float inc = P;
#pragma unroll
    for (int off = 1; off < LPR; off <<= 1) {
        float t = __shfl_up(inc, off, LPR);
        if (sub >= off) inc *= t;
    }
    float Tex = __shfl_up(inc, 1, LPR);
    if (sub == 0) Tex = 1.0f;      // exclusive transmittance at chunk start

    // ---- main serial loop: weights + composites ----------------------------
    float* wp = out_w + (size_t)ray * NSEG + s0;
    float Trun = Tex;
    float sr = 0.f, sg = 0.f, sb = 0.f, sw = 0.f, sd = 0.f;
#pragma unroll
    for (int j = 0; j < SPL; ++j) {
        float alpha = 1.0f - e[j];
        float w = alpha * Trun;
        Trun *= (e[j] + 1e-10f);
        if (!last || j < SPL - 1) wp[j] = w;
        float dm = (d[j] + d[j + 1]) * 0.5f;
        float cr = (c[3 * j + 0] + c[3 * j + 3]) * 0.5f;
        float cg = (c[3 * j + 1] + c[3 * j + 4]) * 0.5f;
        float cb = (c[3 * j + 2] + c[3 * j + 5]) * 0.5f;
        sr += w * cr; sg += w * cg; sb += w * cb;
        sw += w; sd += w * dm;
    }

    // ---- reduce the 5 composites across the 8-lane group -------------------
#pragma unroll
    for (int off = 4; off; off >>= 1) {
        sr += __shfl_xor(sr, off);
        sg += __shfl_xor(sg, off);
        sb += __shfl_xor(sb, off);
        sw += __shfl_xor(sw, off);
        sd += __shfl_xor(sd, off);
    }

    if (sub == 0) {
        float cd = sd / sw;
        if (isnan(cd)) cd = __int_as_float(0x7F800000);  // nan -> +inf
        float gmin = __uint_as_float(mm[0]);
        float gmax = __uint_as_float(mm[1]);
        cd = fminf(fmaxf(cd, gmin), gmax);
        out_depth[ray] = cd;
        out_rgb[(size_t)ray * 3 + 0] = sr * 2.0f - 1.0f;
        out_rgb[(size_t)ray * 3 + 1] = sg * 2.0f - 1.0f;
        out_rgb[(size_t)ray * 3 + 2] = sb * 2.0f - 1.0f;
    }
}

// ---------------------------------------------------------------------------
extern "C" void kernel_launch(void* const* d_in, const int* in_sizes, int n_in,
                              void* d_out, int out_size, void* d_ws, size_t ws_size,
                              hipStream_t stream) {
    const float* colors    = (const float*)d_in[0];
    const float* densities = (const float*)d_in[1];
    const float* depths    = (const float*)d_in[2];

    const int n_rays = in_sizes[1] / NS;  // densities is B*R*S

    float* out       = (float*)d_out;
    float* out_rgb   = out;                              // [n_rays, 3]
    float* out_depth = out + (size_t)n_rays * 3;         // [n_rays, 1]
    float* out_w     = out + (size_t)n_rays * 4;         // [n_rays, 95]

    unsigned* mm = (unsigned*)d_ws;

    hipLaunchKernelGGL(init_mm_kernel, dim3(1), dim3(1), 0, stream, mm);

    const int n4 = n_rays * NS / 4;
    hipLaunchKernelGGL(minmax_kernel, dim3(512), dim3(256), 0, stream,
                       (const float4*)depths, mm, n4);

    hipLaunchKernelGGL(raymarch_kernel,
                       dim3((n_rays + RPB - 1) / RPB), dim3(256), 0, stream,
                       (const float4*)colors, (const float4*)densities,
                       (const float4*)depths, mm,
                       out_rgb, out_depth, out_w, n_rays);
}